// Round 6
// baseline (97.323 us; speedup 1.0000x reference)
//
#include <hip/hip_runtime.h>

#define FR 3
#define KS 7
#define TLX 128
#define TLY 16
#define PPT 4                 // consecutive pixel rows per thread
#define HX (TLX + 2*FR)       // 134
#define HY (TLY + FR)         // 19 (top halo only; half-kernel has dy<=0)
#define LSTR 136              // LDS row stride (floats), 8B-aligned rows
#define IMG_H 512
#define IMG_W 512
#define NB 8
#define NC 3
#define GXB (IMG_W / TLX)     // 4
#define GYB (IMG_H / TLY)     // 32
#define NMAIN (GXB * GYB * NB)    // 1024
#define RIM_PER_IMG 6108          // 512^2 - 506^2
#define NRIM_THREADS (RIM_PER_IMG * NB)          // 48864
#define NRIM_BLK ((NRIM_THREADS + 255) / 256)    // 191
#define NBLK_A (NMAIN + NRIM_BLK)                // 1215
#define NPART NBLK_A

// exp(-50*s) = 2^(-K2*s), K2 = 50*log2(e)=72.13475204444817. Main kernel
// pre-scales inputs by K=sqrt(K2) so exp2 arg is just -(sum of squared diffs).
#define KSC 8.493218f
#define K2F 72.134752f

typedef float v2f __attribute__((ext_vector_type(2)));
__device__ __forceinline__ v2f mk2(float a, float b) { v2f r; r.x = a; r.y = b; return r; }

constexpr double g1d[KS] = {0.011108996538242306, 0.1353352832366127,
                            0.6065306597126334,   1.0,
                            0.6065306597126334,   0.1353352832366127,
                            0.011108996538242306};
constexpr double SUMG = 1.0 + 2.0 * (0.011108996538242306 + 0.1353352832366127
                                     + 0.6065306597126334);
constexpr double INVN = 1.0 / (SUMG * SUMG);
constexpr double KD   = 8.493218;   // must match KSC
constexpr double WPAIR = 2.0 * INVN / KD;   // pair-doubled, un-scaled, normalized

__device__ __forceinline__ int refl(int i, int n) {
    i = (i < 0) ? -i : i;
    return (i >= n) ? (2*n - 2 - i) : i;
}

// Fused kernel. Blocks [0, NRIM_BLK) = rim path; rest = main path.
__global__ __launch_bounds__(256) void blt_fused(const float* __restrict__ in,
                                                 float* __restrict__ partial) {
    __shared__ float sm[NC][HY][LSTR];   // 3*19*136*4 = 31008 B
    __shared__ float wsum[4];
    const int tid = threadIdx.x;
    float a = 0.0f;

    if (blockIdx.x >= NRIM_BLK) {
        // ---- main path ----
        const int bid = blockIdx.x - NRIM_BLK;
        const int b   = bid >> 7;            // 128 blocks per image (4 x 32)
        const int rem = bid & 127;
        const int by  = (rem >> 2) * TLY;
        const int bx  = (rem & 3) * TLX;
        const int tx  = tid & 63;            // pixel pair column index
        const int ty  = tid >> 6;            // 0..3 -> 4-row strip
        const float* base = in + (size_t)b * NC * IMG_H * IMG_W;

        // Stage reflect-padded halo tile (top+side), pre-scaled by K.
        for (int idx = tid; idx < HY * HX; idx += 256) {
            int ly = idx / HX;
            int lx = idx - ly * HX;
            int gy = refl(by + ly - FR, IMG_H);
            int gx = refl(bx + lx - FR, IMG_W);
            #pragma unroll
            for (int c = 0; c < NC; ++c)
                sm[c][ly][lx] = base[(c * IMG_H + gy) * IMG_W + gx] * KSC;
        }
        __syncthreads();

        // Per-pixel-column masked weights, packed: {pixel0, pixel1} per l.
        const int x0 = bx + 2 * tx;
        v2f glmv[KS];
        #pragma unroll
        for (int l = 0; l < KS; ++l) {
            float m0 = ((unsigned)(x0 + l - FR)     < (unsigned)IMG_W) ? (float)(g1d[l] * WPAIR) : 0.0f;
            float m1 = ((unsigned)(x0 + 1 + l - FR) < (unsigned)IMG_W) ? (float)(g1d[l] * WPAIR) : 0.0f;
            glmv[l] = mk2(m0, m1);
        }

        const int r0 = ty * PPT;
        v2f ccv[PPT][NC];
        v2f acc[PPT];
        #pragma unroll
        for (int i = 0; i < PPT; ++i) acc[i] = mk2(0.0f, 0.0f);

        // Descending halo rows: pixel-row i's center row (rr=i+3) comes first,
        // so centers are captured from the row window (no extra reads).
        #pragma unroll
        for (int rr = KS - 1; rr >= 0; --rr) {
            // Row window w[0..7] per channel, loaded ONCE through volatile LDS
            // pointers (volatile loads cannot be rematerialized at each use —
            // this is the whole point; VGPR_Count=24 in earlier rounds proved
            // the compiler was re-issuing ds_reads per tap).
            v2f wp[NC][KS];
            #pragma unroll
            for (int c = 0; c < NC; ++c) {
                const volatile v2f* rowp =
                    reinterpret_cast<const volatile v2f*>(&sm[c][r0 + rr][2 * tx]);
                v2f p0 = rowp[0];
                v2f p1 = rowp[1];
                v2f p2 = rowp[2];
                v2f p3 = rowp[3];
                wp[c][0] = p0;
                wp[c][1] = mk2(p0.y, p1.x);
                wp[c][2] = p1;
                wp[c][3] = mk2(p1.y, p2.x);
                wp[c][4] = p2;
                wp[c][5] = mk2(p2.y, p3.x);
                wp[c][6] = p3;
            }
            #pragma unroll
            for (int i = 0; i < PPT; ++i) {
                const int k = rr - i;                 // dy + 3
                if (k < 0 || k > FR) continue;        // compile-time
                if (k == FR) {                        // center row: capture centers
                    ccv[i][0] = wp[0][3];
                    ccv[i][1] = wp[1][3];
                    ccv[i][2] = wp[2][3];
                }
                const int lmax = (k == FR) ? FR : KS; // dy==0: left cols only
                const float rw = (by + r0 + rr >= FR) ? (float)g1d[k] : 0.0f;
                v2f t = mk2(0.0f, 0.0f);
                #pragma unroll
                for (int l = 0; l < KS; ++l) {
                    if (l >= lmax) continue;          // compile-time
                    v2f d0 = ccv[i][0] - wp[0][l];
                    v2f d1 = ccv[i][1] - wp[1][l];
                    v2f d2 = ccv[i][2] - wp[2][l];
                    v2f s  = d0 * d0;
                    s = __builtin_elementwise_fma(d1, d1, s);
                    s = __builtin_elementwise_fma(d2, d2, s);
                    v2f e;
                    e.x = __builtin_amdgcn_exp2f(-s.x);
                    e.y = __builtin_amdgcn_exp2f(-s.y);
                    float sax = fabsf(d0.x) + fabsf(d1.x);
                    sax += fabsf(d2.x);
                    float say = fabsf(d0.y) + fabsf(d1.y);
                    say += fabsf(d2.y);
                    t = __builtin_elementwise_fma(mk2(sax, say), e * glmv[l], t);
                }
                acc[i] = __builtin_elementwise_fma(t, mk2(rw, rw), acc[i]);
            }
            // Keep each row's loads+math contained so the unroll doesn't hoist
            // all 84 ds_reads and blow up register pressure.
            __builtin_amdgcn_sched_barrier(0);
        }
        v2f av = (acc[0] + acc[1]) + (acc[2] + acc[3]);
        a = av.x + av.y;
    } else {
        // ---- rim path: taps whose partner is out-of-image, counted once ----
        const int idx = blockIdx.x * 256 + tid;
        if (idx < NRIM_THREADS) {
            const int b = idx / RIM_PER_IMG;
            int r = idx - b * RIM_PER_IMG;
            int y, x;
            if (r < 3 * IMG_W) { y = r >> 9; x = r & (IMG_W - 1); }
            else if (r < 6 * IMG_W) { r -= 3 * IMG_W; y = (IMG_H - 3) + (r >> 9); x = r & (IMG_W - 1); }
            else if (r < 6 * IMG_W + 3 * (IMG_H - 6)) { r -= 6 * IMG_W; y = 3 + r / 3; x = r - 3 * (r / 3); }
            else { r -= 6 * IMG_W + 3 * (IMG_H - 6); y = 3 + r / 3; x = (IMG_W - 3) + (r - 3 * (r / 3)); }

            const float* base = in + (size_t)b * NC * IMG_H * IMG_W;
            const float cc0 = base[(0 * IMG_H + y) * IMG_W + x];
            const float cc1 = base[(1 * IMG_H + y) * IMG_W + x];
            const float cc2 = base[(2 * IMG_H + y) * IMG_W + x];

            #pragma unroll
            for (int k = 0; k < KS; ++k) {
                #pragma unroll
                for (int l = 0; l < KS; ++l) {
                    if (k == FR && l == FR) continue;
                    int qy = y + k - FR, qx = x + l - FR;
                    bool oob = ((unsigned)qy >= (unsigned)IMG_H) | ((unsigned)qx >= (unsigned)IMG_W);
                    if (oob) {
                        int ry = refl(qy, IMG_H), rx = refl(qx, IMG_W);
                        float v0 = base[(0 * IMG_H + ry) * IMG_W + rx];
                        float v1 = base[(1 * IMG_H + ry) * IMG_W + rx];
                        float v2 = base[(2 * IMG_H + ry) * IMG_W + rx];
                        float d0 = cc0 - v0, d1 = cc1 - v1, d2 = cc2 - v2;
                        float s = d0 * d0;
                        s = fmaf(d1, d1, s);
                        s = fmaf(d2, d2, s);
                        float e = __builtin_amdgcn_exp2f(-(K2F * s));
                        float sa = fabsf(d0) + fabsf(d1) + fabsf(d2);
                        a = fmaf(sa, e * (float)(g1d[k] * g1d[l] * INVN), a);
                    }
                }
            }
        }
        __syncthreads();
    }

    // Block reduction -> one partial per block.
    #pragma unroll
    for (int off = 32; off > 0; off >>= 1)
        a += __shfl_down(a, off, 64);
    if ((tid & 63) == 0) wsum[tid >> 6] = a;
    __syncthreads();
    if (tid == 0)
        partial[blockIdx.x] = wsum[0] + wsum[1] + wsum[2] + wsum[3];
}

__global__ __launch_bounds__(256) void finalize_kernel(const float* __restrict__ partial,
                                                       float* __restrict__ out) {
    __shared__ float wsum[4];
    const int tid = threadIdx.x;
    float a = 0.0f;
    for (int i = tid; i < NPART; i += 256) a += partial[i];
    #pragma unroll
    for (int off = 32; off > 0; off >>= 1)
        a += __shfl_down(a, off, 64);
    if ((tid & 63) == 0) wsum[tid >> 6] = a;
    __syncthreads();
    if (tid == 0)
        out[0] = (wsum[0] + wsum[1] + wsum[2] + wsum[3]) / (float)(NB * NC * IMG_H * IMG_W);
}

extern "C" void kernel_launch(void* const* d_in, const int* in_sizes, int n_in,
                              void* d_out, int out_size, void* d_ws, size_t ws_size,
                              hipStream_t stream) {
    const float* in = (const float*)d_in[0];
    float* out = (float*)d_out;
    float* ws  = (float*)d_ws;      // NPART partials; every slot written each call

    blt_fused<<<NBLK_A, 256, 0, stream>>>(in, ws);
    finalize_kernel<<<1, 256, 0, stream>>>(ws, out);
}

// Round 7
// 90.830 us; speedup vs baseline: 1.0715x; 1.0715x over previous
//
#include <hip/hip_runtime.h>

#define FR 3
#define KS 7
#define TLX 64
#define TLY 16
#define PPT 2                 // consecutive pixel rows per thread
#define HX (TLX + 2*FR)       // 70
#define HY (TLY + FR)         // 19 (top halo only; half-kernel has dy<=0)
#define LSTR 72               // LDS row stride (floats), 8B-aligned rows
#define IMG_H 512
#define IMG_W 512
#define NB 8
#define NC 3
#define GXB (IMG_W / TLX)     // 8
#define GYB (IMG_H / TLY)     // 32
#define NMAIN (GXB * GYB * NB)    // 2048
#define RIM_PER_IMG 6108          // 512^2 - 506^2
#define NRIM_THREADS (RIM_PER_IMG * NB)          // 48864
#define NRIM_BLK ((NRIM_THREADS + 255) / 256)    // 191
#define NBLK_A (NMAIN + NRIM_BLK)                // 2239
#define NPART NBLK_A

// exp(-50*s) = 2^(-K2*s), K2 = 50*log2(e)=72.13475204444817. Main kernel
// pre-scales inputs by K=sqrt(K2) so exp2 arg is just -(sum of squared diffs).
#define KSC 8.493218f
#define K2F 72.134752f

typedef float v2f __attribute__((ext_vector_type(2)));
__device__ __forceinline__ v2f mk2(float a, float b) { v2f r; r.x = a; r.y = b; return r; }

constexpr double g1d[KS] = {0.011108996538242306, 0.1353352832366127,
                            0.6065306597126334,   1.0,
                            0.6065306597126334,   0.1353352832366127,
                            0.011108996538242306};
constexpr double SUMG = 1.0 + 2.0 * (0.011108996538242306 + 0.1353352832366127
                                     + 0.6065306597126334);
constexpr double INVN = 1.0 / (SUMG * SUMG);
constexpr double KD   = 8.493218;   // must match KSC
constexpr double WPAIR = 2.0 * INVN / KD;   // pair-doubled, un-scaled, normalized

__device__ __forceinline__ int refl(int i, int n) {
    i = (i < 0) ? -i : i;
    return (i >= n) ? (2*n - 2 - i) : i;
}

// Fused kernel. Blocks [0, NRIM_BLK) = rim path (latency-bound, scheduled first);
// blocks [NRIM_BLK, NBLK_A) = main path.
// LDS = 16.4 KB -> 8 blocks/CU = 32 waves/CU (hardware max occupancy).
__global__ __launch_bounds__(256) void blt_fused(const float* __restrict__ in,
                                                 float* __restrict__ partial) {
    __shared__ float sm[NC][HY][LSTR];   // 3*19*72*4 = 16416 B
    __shared__ float wsum[4];
    const int tid = threadIdx.x;
    float a = 0.0f;

    if (blockIdx.x >= NRIM_BLK) {
        // ---- main path ----
        const int bid = blockIdx.x - NRIM_BLK;
        const int b   = bid >> 8;            // 256 blocks per image (8 x 32)
        const int rem = bid & 255;
        const int by  = (rem >> 3) * TLY;
        const int bx  = (rem & 7) * TLX;
        const int tx  = tid & 31;            // pair-column 0..31
        const int ty  = tid >> 5;            // 0..7 -> 2-row strip
        const float* base = in + (size_t)b * NC * IMG_H * IMG_W;

        // Stage reflect-padded halo tile (top+side), pre-scaled by K.
        for (int idx = tid; idx < HY * HX; idx += 256) {
            int ly = idx / HX;
            int lx = idx - ly * HX;
            int gy = refl(by + ly - FR, IMG_H);
            int gx = refl(bx + lx - FR, IMG_W);
            #pragma unroll
            for (int c = 0; c < NC; ++c)
                sm[c][ly][lx] = base[(c * IMG_H + gy) * IMG_W + gx] * KSC;
        }
        __syncthreads();

        // Per-pixel-column masked weights, packed: {pixel0, pixel1} per l.
        const int x0 = bx + 2 * tx;
        v2f glmv[KS];
        #pragma unroll
        for (int l = 0; l < KS; ++l) {
            float m0 = ((unsigned)(x0 + l - FR)     < (unsigned)IMG_W) ? (float)(g1d[l] * WPAIR) : 0.0f;
            float m1 = ((unsigned)(x0 + 1 + l - FR) < (unsigned)IMG_W) ? (float)(g1d[l] * WPAIR) : 0.0f;
            glmv[l] = mk2(m0, m1);
        }

        const int r0 = ty * PPT;
        v2f ccv[PPT][NC];
        v2f acc[PPT];
        #pragma unroll
        for (int i = 0; i < PPT; ++i) acc[i] = mk2(0.0f, 0.0f);

        // Descending halo rows: pixel-row i's center row (rr=i+3) comes first,
        // so centers are captured from the row window (no extra reads).
        #pragma unroll
        for (int rr = PPT + FR - 1; rr >= 0; --rr) {   // 5 windows
            v2f wp[NC][KS];
            #pragma unroll
            for (int c = 0; c < NC; ++c) {
                v2f p0 = *reinterpret_cast<const v2f*>(&sm[c][r0 + rr][2 * tx + 0]);
                v2f p1 = *reinterpret_cast<const v2f*>(&sm[c][r0 + rr][2 * tx + 2]);
                v2f p2 = *reinterpret_cast<const v2f*>(&sm[c][r0 + rr][2 * tx + 4]);
                v2f p3 = *reinterpret_cast<const v2f*>(&sm[c][r0 + rr][2 * tx + 6]);
                wp[c][0] = p0;
                wp[c][1] = mk2(p0.y, p1.x);
                wp[c][2] = p1;
                wp[c][3] = mk2(p1.y, p2.x);
                wp[c][4] = p2;
                wp[c][5] = mk2(p2.y, p3.x);
                wp[c][6] = p3;
            }
            #pragma unroll
            for (int i = 0; i < PPT; ++i) {
                const int k = rr - i;                 // dy + 3
                if (k < 0 || k > FR) continue;        // compile-time
                if (k == FR) {                        // center row: capture centers
                    ccv[i][0] = wp[0][3];
                    ccv[i][1] = wp[1][3];
                    ccv[i][2] = wp[2][3];
                }
                const int lmax = (k == FR) ? FR : KS; // dy==0: left cols only
                const float rw = (by + r0 + rr >= FR) ? (float)g1d[k] : 0.0f;
                v2f t = mk2(0.0f, 0.0f);
                #pragma unroll
                for (int l = 0; l < KS; ++l) {
                    if (l >= lmax) continue;          // compile-time
                    v2f d0 = ccv[i][0] - wp[0][l];
                    v2f d1 = ccv[i][1] - wp[1][l];
                    v2f d2 = ccv[i][2] - wp[2][l];
                    v2f s  = d0 * d0;
                    s = __builtin_elementwise_fma(d1, d1, s);
                    s = __builtin_elementwise_fma(d2, d2, s);
                    v2f e;
                    e.x = __builtin_amdgcn_exp2f(-s.x);
                    e.y = __builtin_amdgcn_exp2f(-s.y);
                    float sax = fabsf(d0.x) + fabsf(d1.x);
                    sax += fabsf(d2.x);
                    float say = fabsf(d0.y) + fabsf(d1.y);
                    say += fabsf(d2.y);
                    t = __builtin_elementwise_fma(mk2(sax, say), e * glmv[l], t);
                }
                acc[i] = __builtin_elementwise_fma(t, mk2(rw, rw), acc[i]);
            }
        }
        v2f av = acc[0] + acc[1];
        a = av.x + av.y;
    } else {
        // ---- rim path: taps whose partner is out-of-image, counted once ----
        const int idx = blockIdx.x * 256 + tid;
        if (idx < NRIM_THREADS) {
            const int b = idx / RIM_PER_IMG;
            int r = idx - b * RIM_PER_IMG;
            int y, x;
            if (r < 3 * IMG_W) { y = r >> 9; x = r & (IMG_W - 1); }
            else if (r < 6 * IMG_W) { r -= 3 * IMG_W; y = (IMG_H - 3) + (r >> 9); x = r & (IMG_W - 1); }
            else if (r < 6 * IMG_W + 3 * (IMG_H - 6)) { r -= 6 * IMG_W; y = 3 + r / 3; x = r - 3 * (r / 3); }
            else { r -= 6 * IMG_W + 3 * (IMG_H - 6); y = 3 + r / 3; x = (IMG_W - 3) + (r - 3 * (r / 3)); }

            const float* base = in + (size_t)b * NC * IMG_H * IMG_W;
            const float cc0 = base[(0 * IMG_H + y) * IMG_W + x];
            const float cc1 = base[(1 * IMG_H + y) * IMG_W + x];
            const float cc2 = base[(2 * IMG_H + y) * IMG_W + x];

            #pragma unroll
            for (int k = 0; k < KS; ++k) {
                #pragma unroll
                for (int l = 0; l < KS; ++l) {
                    if (k == FR && l == FR) continue;
                    int qy = y + k - FR, qx = x + l - FR;
                    bool oob = ((unsigned)qy >= (unsigned)IMG_H) | ((unsigned)qx >= (unsigned)IMG_W);
                    if (oob) {
                        int ry = refl(qy, IMG_H), rx = refl(qx, IMG_W);
                        float v0 = base[(0 * IMG_H + ry) * IMG_W + rx];
                        float v1 = base[(1 * IMG_H + ry) * IMG_W + rx];
                        float v2 = base[(2 * IMG_H + ry) * IMG_W + rx];
                        float d0 = cc0 - v0, d1 = cc1 - v1, d2 = cc2 - v2;
                        float s = d0 * d0;
                        s = fmaf(d1, d1, s);
                        s = fmaf(d2, d2, s);
                        float e = __builtin_amdgcn_exp2f(-(K2F * s));
                        float sa = fabsf(d0) + fabsf(d1) + fabsf(d2);
                        a = fmaf(sa, e * (float)(g1d[k] * g1d[l] * INVN), a);
                    }
                }
            }
        }
        __syncthreads();
    }

    // Block reduction -> one partial per block.
    #pragma unroll
    for (int off = 32; off > 0; off >>= 1)
        a += __shfl_down(a, off, 64);
    if ((tid & 63) == 0) wsum[tid >> 6] = a;
    __syncthreads();
    if (tid == 0)
        partial[blockIdx.x] = wsum[0] + wsum[1] + wsum[2] + wsum[3];
}

__global__ __launch_bounds__(256) void finalize_kernel(const float* __restrict__ partial,
                                                       float* __restrict__ out) {
    __shared__ float wsum[4];
    const int tid = threadIdx.x;
    float a = 0.0f;
    for (int i = tid; i < NPART; i += 256) a += partial[i];
    #pragma unroll
    for (int off = 32; off > 0; off >>= 1)
        a += __shfl_down(a, off, 64);
    if ((tid & 63) == 0) wsum[tid >> 6] = a;
    __syncthreads();
    if (tid == 0)
        out[0] = (wsum[0] + wsum[1] + wsum[2] + wsum[3]) / (float)(NB * NC * IMG_H * IMG_W);
}

extern "C" void kernel_launch(void* const* d_in, const int* in_sizes, int n_in,
                              void* d_out, int out_size, void* d_ws, size_t ws_size,
                              hipStream_t stream) {
    const float* in = (const float*)d_in[0];
    float* out = (float*)d_out;
    float* ws  = (float*)d_ws;      // NPART partials; every slot written each call

    blt_fused<<<NBLK_A, 256, 0, stream>>>(in, ws);
    finalize_kernel<<<1, 256, 0, stream>>>(ws, out);
}